// Round 19
// baseline (363.477 us; speedup 1.0000x reference)
//
#include <hip/hip_runtime.h>

typedef __bf16 bf16;
typedef bf16 bf16x8 __attribute__((ext_vector_type(8)));
typedef float f32x4 __attribute__((ext_vector_type(4)));

#define BB 8
#define TT 8
#define SS 196
#define NTOK 1568           // T*S
#define ROWS 12544          // B*NTOK
#define HH 768
#define HD 64

__device__ __forceinline__ void gload16(const void* g, void* l) {
  __builtin_amdgcn_global_load_lds(
      (const __attribute__((address_space(1))) void*)g,
      (__attribute__((address_space(3))) void*)l, 16, 0, 0);
}

// ---------------- weight transposes f32[K][N] -> bf16[N][K] -----------------
__global__ __launch_bounds__(256)
void transpose_qkv(const float* __restrict__ in0, const float* __restrict__ in1,
                   bf16* __restrict__ out0, bf16* __restrict__ out1) {
  const int K = 768, N = 2304;
  const float* in = blockIdx.z ? in1 : in0;
  bf16* out = blockIdx.z ? out1 : out0;
  __shared__ float tile[64][65];
  const int k0 = blockIdx.x * 64, n0 = blockIdx.y * 64;
  const int tx = threadIdx.x & 63, ty = threadIdx.x >> 6;
  #pragma unroll
  for (int rr = ty; rr < 64; rr += 4)
    tile[rr][tx] = in[(size_t)(k0 + rr) * N + n0 + tx];
  __syncthreads();
  #pragma unroll
  for (int rr = ty; rr < 64; rr += 4)
    out[(size_t)(n0 + rr) * K + k0 + tx] = (bf16)tile[tx][rr];
}

// 768x768 set: z 0->proj_s, 1->proj_t, 2..5 -> down expert (z-2).
__global__ __launch_bounds__(256)
void transpose_768(const float* __restrict__ ps, const float* __restrict__ pt,
                   const float* __restrict__ dw,
                   bf16* __restrict__ ops, bf16* __restrict__ opt,
                   bf16* __restrict__ odw) {
  const int K = 768, N = 768;
  const int z = blockIdx.z;
  const float* in;
  bf16* out;
  if (z == 0)      { in = ps; out = ops; }
  else if (z == 1) { in = pt; out = opt; }
  else             { in = dw + (size_t)(z - 2) * K * N; out = odw + (size_t)(z - 2) * K * N; }
  __shared__ float tile[64][65];
  const int k0 = blockIdx.x * 64, n0 = blockIdx.y * 64;
  const int tx = threadIdx.x & 63, ty = threadIdx.x >> 6;
  #pragma unroll
  for (int rr = ty; rr < 64; rr += 4)
    tile[rr][tx] = in[(size_t)(k0 + rr) * N + n0 + tx];
  __syncthreads();
  #pragma unroll
  for (int rr = ty; rr < 64; rr += 4)
    out[(size_t)(n0 + rr) * K + k0 + tx] = (bf16)tile[tx][rr];
}

// gate_up transpose with column permutation: each 64-row stripe of guT =
// 32 gate rows + their 32 matching up rows (enables in-lane silu fusion).
__global__ __launch_bounds__(256)
void transpose_gu(const float* __restrict__ in, bf16* __restrict__ out) {
  const int K = 768, N = 1536;
  in  += (size_t)blockIdx.z * K * N;
  out += (size_t)blockIdx.z * K * N;
  __shared__ float tile[64][65];
  const int k0 = blockIdx.x * 64, n0 = blockIdx.y * 64;
  const int tx = threadIdx.x & 63, ty = threadIdx.x >> 6;
  const int s = n0 >> 6;
  #pragma unroll
  for (int rr = ty; rr < 64; rr += 4) {
    const int src = (tx < 32) ? (s * 32 + tx) : (768 + s * 32 + tx - 32);
    tile[rr][tx] = in[(size_t)(k0 + rr) * N + src];
  }
  __syncthreads();
  #pragma unroll
  for (int rr = ty; rr < 64; rr += 4)
    out[(size_t)(n0 + rr) * K + k0 + tx] = (bf16)tile[tx][rr];
}

// ---------------- layernorm: TI in -> bf16 out, wave per row ----------------
template<typename TI>
__global__ __launch_bounds__(256)
void ln_kernel(const TI* __restrict__ x, const float* __restrict__ g,
               const float* __restrict__ b, bf16* __restrict__ out) {
  const int row = blockIdx.x * 4 + (threadIdx.x >> 6);
  const int lane = threadIdx.x & 63;
  const TI* xr = x + (size_t)row * HH;
  float v[12];
  float sum = 0.f, sq = 0.f;
  #pragma unroll
  for (int i = 0; i < 12; ++i) {
    v[i] = (float)xr[lane + i * 64];
    sum += v[i];
    sq += v[i] * v[i];
  }
  #pragma unroll
  for (int off = 32; off > 0; off >>= 1) {
    sum += __shfl_xor(sum, off);
    sq  += __shfl_xor(sq, off);
  }
  const float mean = sum * (1.f / 768.f);
  const float var = sq * (1.f / 768.f) - mean * mean;
  const float inv = rsqrtf(var + 1e-6f);
  bf16* op = out + (size_t)row * HH;
  #pragma unroll
  for (int i = 0; i < 12; ++i) {
    const int c = lane + i * 64;
    op[c] = (bf16)((v[i] - mean) * inv * g[c] + b[c]);
  }
}

// layernorm (bf16 in) + expert permutation: row (b,n) -> inv[n]*8 + b.
__global__ __launch_bounds__(256)
void ln_moe_kernel(const bf16* __restrict__ x, const float* __restrict__ g,
                   const float* __restrict__ b, const int* __restrict__ invp,
                   bf16* __restrict__ out) {
  const int row = blockIdx.x * 4 + (threadIdx.x >> 6);
  const int lane = threadIdx.x & 63;
  const bf16* xr = x + (size_t)row * HH;
  float v[12];
  float sum = 0.f, sq = 0.f;
  #pragma unroll
  for (int i = 0; i < 12; ++i) {
    v[i] = (float)xr[lane + i * 64];
    sum += v[i];
    sq += v[i] * v[i];
  }
  #pragma unroll
  for (int off = 32; off > 0; off >>= 1) {
    sum += __shfl_xor(sum, off);
    sq  += __shfl_xor(sq, off);
  }
  const float mean = sum * (1.f / 768.f);
  const float var = sq * (1.f / 768.f) - mean * mean;
  const float inv = rsqrtf(var + 1e-6f);
  const int bb = row / NTOK, n = row - bb * NTOK;
  bf16* op = out + ((size_t)invp[n] * 8 + bb) * HH;
  #pragma unroll
  for (int i = 0; i < 12; ++i) {
    const int c = lane + i * 64;
    op[c] = (bf16)((v[i] - mean) * inv * g[c] + b[c]);
  }
}

// ---------------- K64T GEMM (qkv): 128x64, BK=64, 2 bufs, 3 blk/CU ----------
// R19: maximize barrier-domain count. 48KB LDS (2 x 24KB) -> 3 blocks/CU;
// acc[4][2]=32 AGPR + ~80 VGPR ~= 112 -> 4 waves/SIMD -> 12 waves/CU in 3
// independent barrier domains (vs 8 in 2 for K64). Same 12-phase single-
// barrier schedule: vmcnt -> barrier -> {12 ds_read_b128 || stage t+1
// (t>=1)} -> setprio(1) 16 MFMA setprio(0). buf[t&1]; stage(t+1)@phase t
// targets buf whose reads finished in phase t-1 (phase-t barrier proves).
// vmcnt(6)@p0 (tile0 under tile1's 6 loads), vmcnt(0) after (stage issued a
// full phase earlier). Swizzle: store seg (c&7)^(row&7), read chunk
// ((kg*4+lg)^(lr&7)) (rule #21, conflict-free). Grid 98x36, n-fastest XCD.
__global__ __launch_bounds__(256, 3)
void gemmK64T(const bf16* __restrict__ A, const bf16* __restrict__ BT,
              const float* __restrict__ bias, bf16* __restrict__ outB,
              int N, int K, int NMT) {
  __shared__ __align__(16) bf16 lds[2 * 12288];   // 48 KB
  const int tid = threadIdx.x;
  const int G = gridDim.x;
  int work;
  {
    const int q = G >> 3, r = G & 7, xcd = blockIdx.x & 7, pos = blockIdx.x >> 3;
    work = (xcd < r ? xcd * (q + 1) : r * (q + 1) + (xcd - r) * q) + pos;
  }
  const int mt = work / NMT, nt = work % NMT;     // n-fastest
  const int M0 = mt * 128, N0 = nt * 64;

  const int w = tid >> 6, lane = tid & 63;
  const int wr = w >> 1, wc = w & 1;
  const int lr = lane & 15, lg = lane >> 4;

  // staging: A 1024 chunks (c = tid + i*256, i<4), B 512 chunks (i<2).
  // chunk c -> row c>>3, store seg c&7, source seg (c&7)^(row&7).
  size_t aG[4], bG[2]; int aL[4], bL[2];
  #pragma unroll
  for (int i = 0; i < 4; ++i) {
    const int c = tid + i * 256;
    const int row = c >> 3, seg = (c & 7) ^ (row & 7);
    aG[i] = (size_t)(M0 + row) * K + seg * 8;
    aL[i] = c * 8;
  }
  #pragma unroll
  for (int i = 0; i < 2; ++i) {
    const int c = tid + i * 256;
    const int row = c >> 3, seg = (c & 7) ^ (row & 7);
    bG[i] = (size_t)(N0 + row) * K + seg * 8;
    bL[i] = 8192 + c * 8;
  }
  auto STG = [&](int kt) {
    bf16* buf = lds + (kt & 1) * 12288;
    const int ko = kt << 6;
    #pragma unroll
    for (int i = 0; i < 4; ++i) gload16(A + aG[i] + ko, buf + aL[i]);
    #pragma unroll
    for (int i = 0; i < 2; ++i) gload16(BT + bG[i] + ko, buf + bL[i]);
  };

  f32x4 acc[4][2] = {};
  const int NT = K >> 6;                          // 12 at K=768

  STG(0); STG(1);

  for (int t = 0; t < NT; ++t) {
    if (t == 0) { asm volatile("s_waitcnt vmcnt(6)" ::: "memory"); }
    else        { asm volatile("s_waitcnt vmcnt(0)" ::: "memory"); }
    __builtin_amdgcn_s_barrier();
    asm volatile("" ::: "memory");

    const bf16* Ab = lds + (t & 1) * 12288;
    const bf16* Bb = Ab + 8192;
    bf16x8 a[8], b[4];
    #pragma unroll
    for (int mf = 0; mf < 4; ++mf) {
      const int row = wr * 64 + mf * 16 + lr;
      #pragma unroll
      for (int kg = 0; kg < 2; ++kg)
        a[mf * 2 + kg] = *(const bf16x8*)(Ab + row * 64 + ((kg * 4 + lg) ^ (lr & 7)) * 8);
    }
    #pragma unroll
    for (int nf = 0; nf < 2; ++nf) {
      const int row = wc * 32 + nf * 16 + lr;
      #pragma unroll
      for (int kg = 0; kg < 2; ++kg)
        b[nf * 2 + kg] = *(const bf16x8*)(Bb + row * 64 + ((kg * 4 + lg) ^ (lr & 7)) * 8);
    }
    if (t >= 1 && t + 1 < NT) STG(t + 1);

    __builtin_amdgcn_s_setprio(1);
    #pragma unroll
    for (int mf = 0; mf < 4; ++mf)
      #pragma unroll
      for (int nf = 0; nf < 2; ++nf) {
        f32x4 c = acc[mf][nf];
        c = __builtin_amdgcn_mfma_f32_16x16x32_bf16(a[mf * 2 + 0], b[nf * 2 + 0], c, 0, 0, 0);
        c = __builtin_amdgcn_mfma_f32_16x16x32_bf16(a[mf * 2 + 1], b[nf * 2 + 1], c, 0, 0, 0);
        acc[mf][nf] = c;
      }
    __builtin_amdgcn_s_setprio(0);
    asm volatile("" ::: "memory");
  }

  #pragma unroll
  for (int m = 0; m < 4; ++m) {
    #pragma unroll
    for (int j = 0; j < 4; ++j) {
      const size_t rbase = (size_t)(M0 + wr * 64 + m * 16 + lg * 4 + j) * N;
      #pragma unroll
      for (int n = 0; n < 2; ++n) {
        const int gcol = N0 + wc * 32 + n * 16 + lr;
        outB[rbase + gcol] = (bf16)(acc[m][n][j] + bias[gcol]);
      }
    }
  }
}

// ---------------- K64 GEMM: 128x128, BK=64, 2 bufs, 12 phases, 2 blk/CU -----
// (gate_up MOE+GUFUSE path; unchanged from R18.)
template<bool MOE, bool GUFUSE>
__global__ __launch_bounds__(256, 2)
void gemmK64(const bf16* __restrict__ A, const bf16* __restrict__ BT,
             const float* __restrict__ bias, bf16* __restrict__ outB,
             int N, int K, int NMT,
             const int4* __restrict__ descs, const int* __restrict__ meta) {
  __shared__ __align__(16) bf16 lds[2 * 16384];   // 64 KB
  const int tid = threadIdx.x;
  const int G = gridDim.x;
  int work;
  {
    const int q = G >> 3, r = G & 7, xcd = blockIdx.x & 7, pos = blockIdx.x >> 3;
    work = (xcd < r ? xcd * (q + 1) : r * (q + 1) + (xcd - r) * q) + pos;
  }
  int M0, N0, ncnt = 16;
  if constexpr (MOE) {
    const int ntile = work % NMT, desc = work / NMT;
    if (desc >= meta[0]) return;
    int4 d = descs[desc];
    BT += (size_t)d.x * N * K;
    ncnt = d.z;
    N0 = ntile * 128;
    M0 = d.y * 8;                                 // permuted-dense A row base
  } else {
    const int mt = work / NMT, nt = work % NMT;   // n-fastest
    M0 = mt * 128;
    N0 = nt * 128;
  }

  const int w = tid >> 6, lane = tid & 63;
  const int wr = w >> 1, wc = w & 1;
  const int lr = lane & 15, lg = lane >> 4;

  size_t aG[4], bG[4]; int L[4];
  #pragma unroll
  for (int i = 0; i < 4; ++i) {
    const int c = tid + i * 256;
    const int row = c >> 3, seg = (c & 7) ^ (row & 7);
    int ar = M0 + row;
    if constexpr (MOE) ar = ar < ROWS ? ar : ROWS - 1;
    aG[i] = (size_t)ar * K + seg * 8;
    bG[i] = (size_t)(N0 + row) * K + seg * 8;
    L[i] = c * 8;
  }
  auto STG = [&](int kt) {
    bf16* buf = lds + (kt & 1) * 16384;
    const int ko = kt << 6;
    #pragma unroll
    for (int i = 0; i < 4; ++i) gload16(A + aG[i] + ko, buf + L[i]);
    #pragma unroll
    for (int i = 0; i < 4; ++i) gload16(BT + bG[i] + ko, buf + 8192 + L[i]);
  };

  f32x4 acc[4][4] = {};
  const int NT = K >> 6;                          // 12 at K=768

  STG(0); STG(1);

  for (int t = 0; t < NT; ++t) {
    if (t == 0) { asm volatile("s_waitcnt vmcnt(8)" ::: "memory"); }
    else        { asm volatile("s_waitcnt vmcnt(0)" ::: "memory"); }
    __builtin_amdgcn_s_barrier();
    asm volatile("" ::: "memory");

    const bf16* Ab = lds + (t & 1) * 16384;
    const bf16* Bb = Ab + 8192;
    bf16x8 a[8], b[8];
    #pragma unroll
    for (int mf = 0; mf < 4; ++mf) {
      const int row = wr * 64 + mf * 16 + lr;
      #pragma unroll
      for (int kg = 0; kg < 2; ++kg)
        a[mf * 2 + kg] = *(const bf16x8*)(Ab + row * 64 + ((kg * 4 + lg) ^ (lr & 7)) * 8);
    }
    #pragma unroll
    for (int nf = 0; nf < 4; ++nf) {
      const int row = wc * 64 + nf * 16 + lr;
      #pragma unroll
      for (int kg = 0; kg < 2; ++kg)
        b[nf * 2 + kg] = *(const bf16x8*)(Bb + row * 64 + ((kg * 4 + lg) ^ (lr & 7)) * 8);
    }
    if (t >= 1 && t + 1 < NT) STG(t + 1);

    __builtin_amdgcn_s_setprio(1);
    #pragma unroll
    for (int mf = 0; mf < 4; ++mf)
      #pragma unroll
      for (int nf = 0; nf < 4; ++nf) {
        f32x4 c = acc[mf][nf];
        c = __builtin_amdgcn_mfma_f32_16x16x32_bf16(a[mf * 2 + 0], b[nf * 2 + 0], c, 0, 0, 0);
        c = __builtin_amdgcn_mfma_f32_16x16x32_bf16(a[mf * 2 + 1], b[nf * 2 + 1], c, 0, 0, 0);
        acc[mf][nf] = c;
      }
    __builtin_amdgcn_s_setprio(0);
    asm volatile("" ::: "memory");
  }

  #pragma unroll
  for (int m = 0; m < 4; ++m) {
    #pragma unroll
    for (int j = 0; j < 4; ++j) {
      const int r = wr * 64 + m * 16 + lg * 4 + j;
      if (MOE && ((r >> 3) >= ncnt)) continue;
      if constexpr (GUFUSE) {
        const size_t rbase = (size_t)(M0 + r) * 768;
        const int stripe = (N0 >> 6) + wc;
        #pragma unroll
        for (int n = 0; n < 2; ++n) {
          const int icol = stripe * 32 + n * 16 + lr;
          const float g = acc[m][n][j], u = acc[m][n + 2][j];
          outB[rbase + icol] = (bf16)(g / (1.f + __expf(-g)) * u);
        }
      } else {
        const size_t rbase = (size_t)(M0 + r) * N;
        #pragma unroll
        for (int n = 0; n < 4; ++n) {
          const int gcol = N0 + wc * 64 + n * 16 + lr;
          outB[rbase + gcol] = (bf16)(acc[m][n][j] + bias[gcol]);
        }
      }
    }
  }
}

// ---------------- deep-pipe GEMM: 128x(NF*32), BK=32, 3 LDS bufs, 2 blk/CU --
// (proj/down NF=8 single round; schedule unchanged.)
template<int NF, bool MOE, bool BIAS, bool RESID, bool RB16, bool OBF16,
         bool GUFUSE, bool SCATTER>
__global__ __launch_bounds__(256, 2)
void gemmDP(const bf16* __restrict__ A, const bf16* __restrict__ BT,
            const float* __restrict__ bias, const void* __restrict__ resid,
            float* __restrict__ outF, bf16* __restrict__ outB,
            int N, int K, int NMT,
            const int* __restrict__ perm, const int4* __restrict__ descs,
            const int* __restrict__ meta) {
  constexpr int BUFE = 4096 + NF * 1024;          // elems per buffer
  __shared__ __align__(16) bf16 lds[3 * BUFE];
  __shared__ int rowLds[128];

  const int tid = threadIdx.x;
  const int G = gridDim.x;
  int work;
  {
    const int q = G >> 3, r = G & 7, xcd = blockIdx.x & 7, pos = blockIdx.x >> 3;
    work = (xcd < r ? xcd * (q + 1) : r * (q + 1) + (xcd - r) * q) + pos;
  }
  int M0 = 0, N0, ncnt = 16;
  if constexpr (MOE) {
    const int ntile = work % NMT, desc = work / NMT;
    if (desc >= meta[0]) return;
    int4 d = descs[desc];
    BT += (size_t)d.x * N * K;
    ncnt = d.z;
    N0 = ntile * (NF * 32);
    M0 = d.y * 8;                       // permuted-dense A row base
    if constexpr (SCATTER) {
      if (tid < 128) {
        const int nl = tid >> 3, b = tid & 7;
        const int n = perm[d.y + (nl < ncnt ? nl : ncnt - 1)];
        rowLds[tid] = b * NTOK + n;
      }
      __syncthreads();
    }
  } else {
    const int mt = work / NMT, nt = work % NMT;   // n-fastest (proven)
    M0 = mt * 128;
    N0 = nt * (NF * 32);
  }

  const int w = tid >> 6, lane = tid & 63;
  const int wr = w >> 1, wc = w & 1;
  const int lr = lane & 15, lg = lane >> 4;

  const int r0 = tid >> 2;                          // 0..63
  const int sseg = ((tid & 3) ^ ((tid >> 3) & 3)) * 8;
  int arow0 = M0 + r0, arow1 = M0 + 64 + r0;
  if constexpr (MOE) {
    arow0 = arow0 < ROWS ? arow0 : ROWS - 1;
    arow1 = arow1 < ROWS ? arow1 : ROWS - 1;
  }
  const bf16* aP0 = A + (size_t)arow0 * K + sseg;
  const bf16* aP1 = A + (size_t)arow1 * K + sseg;
  const bf16* bP[NF / 2];
  #pragma unroll
  for (int i = 0; i < NF / 2; ++i)
    bP[i] = BT + (size_t)(N0 + i * 64 + r0) * K + sseg;

  auto STG = [&](int kt) {
    bf16* buf = lds + (kt % 3) * BUFE;
    const int ko = kt << 5;
    gload16(aP0 + ko, buf + tid * 8);
    gload16(aP1 + ko, buf + 2048 + tid * 8);
    #pragma unroll
    for (int i = 0; i < NF / 2; ++i)
      gload16(bP[i] + ko, buf + 4096 + i * 2048 + tid * 8);
  };

  const int axr = (lg ^ ((lr >> 1) & 3)) * 8;       // read-side chunk XOR

  f32x4 acc[4][NF] = {};
  const int NT = K >> 5;                            // 24 at K=768

  STG(0); STG(1);

  for (int t = 0; t < NT; ++t) {
    if (t + 1 < NT) {
      if constexpr (NF == 8) { asm volatile("s_waitcnt vmcnt(6)" ::: "memory"); }
      else                   { asm volatile("s_waitcnt vmcnt(4)" ::: "memory"); }
    } else {
      asm volatile("s_waitcnt vmcnt(0)" ::: "memory");
    }
    __builtin_amdgcn_s_barrier();
    asm volatile("" ::: "memory");

    const bf16* Ab = lds + (t % 3) * BUFE;
    const bf16* Bb = Ab + 4096;
    bf16x8 a[4], b[NF];
    #pragma unroll
    for (int mf = 0; mf < 4; ++mf) {
      const int row = wr * 64 + mf * 16 + lr;
      a[mf] = *(const bf16x8*)(Ab + row * 32 + axr);
    }
    #pragma unroll
    for (int nf = 0; nf < NF; ++nf) {
      const int row = wc * (NF * 16) + nf * 16 + lr;
      b[nf] = *(const bf16x8*)(Bb + row * 32 + axr);
    }
    if (t + 2 < NT) STG(t + 2);

    __builtin_amdgcn_s_setprio(1);
    #pragma unroll
    for (int mf = 0; mf < 4; ++mf)
      #pragma unroll
      for (int nf = 0; nf < NF; ++nf)
        acc[mf][nf] = __builtin_amdgcn_mfma_f32_16x16x32_bf16(a[mf], b[nf], acc[mf][nf], 0, 0, 0);
    __builtin_amdgcn_s_setprio(0);
    asm volatile("" ::: "memory");
  }

  #pragma unroll
  for (int m = 0; m < 4; ++m) {
    #pragma unroll
    for (int j = 0; j < 4; ++j) {
      const int r = wr * 64 + m * 16 + lg * 4 + j;
      if (MOE && ((r >> 3) >= ncnt)) continue;
      size_t grow;
      if constexpr (MOE && SCATTER) grow = (size_t)rowLds[r];
      else                          grow = (size_t)(M0 + r);
      if constexpr (GUFUSE) {
        const size_t rbase = grow * 768;
        #pragma unroll
        for (int n = 0; n < NF; ++n) {
          if ((n & 3) >= 2) continue;
          const int stripe = (N0 >> 6) + wc * (NF / 4) + (n >> 2);
          const int icol = stripe * 32 + (n & 3) * 16 + lr;
          const float g = acc[m][n][j], u = acc[m][n + 2][j];
          outB[rbase + icol] = (bf16)(g / (1.f + __expf(-g)) * u);
        }
      } else {
        const size_t rbase = grow * N;
        #pragma unroll
        for (int n = 0; n < NF; ++n) {
          const int gcol = N0 + wc * (NF * 16) + n * 16 + lr;
          float v = acc[m][n][j];
          if constexpr (BIAS)  v += bias[gcol];
          if constexpr (RESID) {
            if constexpr (RB16) v += (float)((const bf16*)resid)[rbase + gcol];
            else                v += ((const float*)resid)[rbase + gcol];
          }
          if constexpr (OBF16) outB[rbase + gcol] = (bf16)v;
          else                 outF[rbase + gcol] = v;
        }
      }
    }
  }
}

// ---------------- spatial attention (MFMA): block per (bp, h), 16 waves -----
#define SPAD 208
#define VST 232
__global__ __launch_bounds__(1024, 1)
void attn_spatial(const bf16* __restrict__ qkv, bf16* __restrict__ out) {
  __shared__ __align__(16) bf16 Ks[SPAD * 64];
  __shared__ __align__(16) bf16 Vt[64 * VST];
  __shared__ __align__(16) bf16 Pb[13][16 * VST];

  const int bp = blockIdx.x, h = blockIdx.y;
  const int tid = threadIdx.x;
  const int w = tid >> 6, lane = tid & 63;
  const int lr = lane & 15, lg = lane >> 4;
  const size_t base = (size_t)bp * SS * 2304 + h * HD;

  for (int cb = w * 64; cb < SPAD * 8; cb += 1024) {
    const int c = cb + lane;
    const int row = c >> 3, seg = c & 7;
    const int srow = row < SS ? row : SS - 1;
    const int sseg = seg ^ (row & 7);
    gload16(qkv + base + (size_t)srow * 2304 + 768 + sseg * 8, Ks + cb * 8);
  }
  for (int t = tid; t < 224 * 8; t += 1024) {
    const int k = t >> 3, dseg = t & 7;
    const int sk = k < SS ? k : SS - 1;
    bf16x8 v = *(const bf16x8*)(qkv + base + (size_t)sk * 2304 + 1536 + dseg * 8);
    #pragma unroll
    for (int i = 0; i < 8; ++i) Vt[(dseg * 8 + i) * VST + k] = v[i];
  }
  if (w < 13) {
    bf16* Pw = Pb[w];
    for (int i = lane; i < 256; i += 64)
      Pw[(i >> 4) * VST + 208 + (i & 15)] = (bf16)0.f;
  }
  __syncthreads();

  for (int t = w; t < 13; t += 16) {
    bf16* Pw = Pb[t];
    const int q0 = t * 16;
    const int qr = q0 + lr;
    const bf16* qp = qkv + base + (size_t)(qr < SS ? qr : SS - 1) * 2304 + lg * 8;
    const bf16x8 af0 = *(const bf16x8*)qp;
    const bf16x8 af1 = *(const bf16x8*)(qp + 32);

    f32x4 sc[13];
    #pragma unroll
    for (int f = 0; f < 13; ++f) sc[f] = (f32x4){0.f, 0.f, 0.f, 0.f};
    #pragma unroll
    for (int f = 0; f < 13; ++f) {
      const int key = f * 16 + lr;
      const bf16x8 bv0 = *(const bf16x8*)&Ks[key * 64 + ((lg) ^ (key & 7)) * 8];
      const bf16x8 bv1 = *(const bf16x8*)&Ks[key * 64 + ((4 + lg) ^ (key & 7)) * 8];
      sc[f] = __builtin_amdgcn_mfma_f32_16x16x32_bf16(af0, bv0, sc[f], 0, 0, 0);
      sc[f] = __builtin_amdgcn_mfma_f32_16x16x32_bf16(af1, bv1, sc[f], 0, 0, 0);
    }
    #pragma unroll
    for (int f = 0; f < 13; ++f)
      #pragma unroll
      for (int j = 0; j < 4; ++j) sc[f][j] *= 0.125f;
    if (192 + lr >= SS)
      #pragma unroll
      for (int j = 0; j < 4; ++j) sc[12][j] = -1e30f;

    float mx[4], ls[4];
    #pragma unroll
    for (int j = 0; j < 4; ++j) {
      float m = sc[0][j];
      #pragma unroll
      for (int f = 1; f < 13; ++f) m = fmaxf(m, sc[f][j]);
      #pragma unroll
      for (int off = 1; off < 16; off <<= 1) m = fmaxf(m, __shfl_xor(m, off));
      mx[j] = m;
    }
    #pragma unroll
    for (int j = 0; j < 4; ++j) ls[j] = 0.f;
    #pragma unroll
    for (int f = 0; f < 13; ++f) {
      #pragma unroll
      for (int j = 0; j < 4; ++j) {
        const float p = __expf(sc[f][j] - mx[j]);
        ls[j] += p;
        Pw[(lg * 4 + j) * VST + f * 16 + lr] = (bf16)p;
      }
    }
    #pragma unroll
    for (int j = 0; j < 4; ++j) {
      #pragma unroll
      for (int off = 1; off < 16; off <<= 1) ls[j] += __shfl_xor(ls[j], off);
      ls[j] = 1.f / ls[j];
    }

    f32x4 oacc[4];
    #pragma unroll
    for (int n = 0; n < 4; ++n) oacc[n] = (f32x4){0.f, 0.f, 0.f, 0.f};
    #pragma unroll
    for (int kb = 0; kb < 7; ++kb) {
      const bf16x8 pa = *(const bf16x8*)&Pw[lr * VST + kb * 32 + lg * 8];
      #pragma unroll
      for (int n = 0; n < 4; ++n) {
        const bf16x8 bv = *(const bf16x8*)&Vt[(n * 16 + lr) * VST + kb * 32 + lg * 8];
        oacc[n] = __builtin_amdgcn_mfma_f32_16x16x32_bf16(pa, bv, oacc[n], 0, 0, 0);
      }
    }
    #pragma unroll
    for (int j = 0; j < 4; ++j) {
      const int row = q0 + lg * 4 + j;
      if (row < SS) {
        bf16* op = out + ((size_t)bp * SS + row) * 768 + h * HD;
        #pragma unroll
        for (int n = 0; n < 4; ++n) op[n * 16 + lr] = (bf16)(oacc[n][j] * ls[j]);
      }
    }
  }
}

// ---------------- temporal attention: wave per (b, s, h), T=8 ---------------
__global__ __launch_bounds__(256)
void attn_temporal(const bf16* __restrict__ qkv, bf16* __restrict__ out) {
  const int pair = blockIdx.x * 4 + (threadIdx.x >> 6);
  const int lane = threadIdx.x & 63;
  const int h = pair % 12;
  const int bs = pair / 12;
  const int b = bs / SS, s = bs - b * SS;
  const size_t row0 = (size_t)b * NTOK + s;
  const int q = lane >> 3, k = lane & 7;
  const bf16* qr = qkv + (row0 + (size_t)q * SS) * 2304 + h * HD;
  const bf16* kr = qkv + (row0 + (size_t)k * SS) * 2304 + 768 + h * HD;
  float sc = 0.f;
  #pragma unroll
  for (int j = 0; j < 8; ++j) {
    bf16x8 qv = ((const bf16x8*)qr)[j];
    bf16x8 kv = ((const bf16x8*)kr)[j];
    #pragma unroll
    for (int d = 0; d < 8; ++d) sc += (float)qv[d] * (float)kv[d];
  }
  sc *= 0.125f;
  float mxv = sc;
  #pragma unroll
  for (int off = 1; off < 8; off <<= 1) mxv = fmaxf(mxv, __shfl_xor(mxv, off));
  float p = __expf(sc - mxv);
  float sum = p;
  #pragma unroll
  for (int off = 1; off < 8; off <<= 1) sum += __shfl_xor(sum, off);
  p /= sum;

  const int dg = lane & 7;
  float o[8] = {0, 0, 0, 0, 0, 0, 0, 0};
  #pragma unroll
  for (int kk = 0; kk < 8; ++kk) {
    const float pk = __shfl(p, (lane & 56) + kk);
    const bf16* vr = qkv + (row0 + (size_t)kk * SS) * 2304 + 1536 + h * HD + dg * 8;
    bf16x8 vv = *(const bf16x8*)vr;
    #pragma unroll
    for (int j = 0; j < 8; ++j) o[j] += pk * (float)vv[j];
  }
  bf16* op = out + (row0 + (size_t)q * SS) * 768 + h * HD + dg * 8;
  bf16x8 ov;
  #pragma unroll
  for (int j = 0; j < 8; ++j) ov[j] = (bf16)o[j];
  *(bf16x8*)op = ov;
}

// ---------------- MoE: bucket tokens by expert; perm, inv, 16-pos descs -----
__global__ __launch_bounds__(256)
void sort_moe(const int* __restrict__ eids, int* __restrict__ perm,
              int* __restrict__ invp, int4* __restrict__ descs,
              int* __restrict__ meta) {
  __shared__ int cnt[4], base[4], cur[4];
  const int tid = threadIdx.x;
  if (tid < 4) cnt[tid] = 0;
  __syncthreads();
  for (int n = tid; n < NTOK; n += 256) atomicAdd(&cnt[eids[n]], 1);
  __syncthreads();
  if (tid == 0) {
    int off = 0;
    for (int e = 0; e < 4; ++e) { base[e] = off; cur[e] = off; off += cnt[e]; }
  }
  __syncthreads();
  for (int n = tid; n < NTOK; n += 256) {
    const int pos = atomicAdd(&cur[eids[n]], 1);
    perm[pos] = n;
    invp[n] = pos;
  }
  if (tid == 0) {
    int t = 0;
    for (int e = 0; e < 4; ++e)
      for (int st = 0; st < cnt[e]; st += 16) {
        const int c = cnt[e] - st;
        descs[t++] = make_int4(e, base[e] + st, c < 16 ? c : 16, 0);
      }
    meta[0] = t;
  }
}

// ---------------- launch ------------------------------------------------------
extern "C" void kernel_launch(void* const* d_in, const int* in_sizes, int n_in,
                              void* d_out, int out_size, void* d_ws, size_t ws_size,
                              hipStream_t stream) {
  (void)in_sizes; (void)n_in; (void)out_size; (void)ws_size;
  const float* x        = (const float*)d_in[0];
  const float* qkv_w_s  = (const float*)d_in[1];
  const float* qkv_b_s  = (const float*)d_in[2];
  const float* proj_w_s = (const float*)d_in[3];
  const float* proj_b_s = (const float*)d_in[4];
  const float* qkv_w_t  = (const float*)d_in[5];
  const float* qkv_b_t  = (const float*)d_in[6];
  const float* proj_w_t = (const float*)d_in[7];
  const float* proj_b_t = (const float*)d_in[8];
  const float* ln_s_g   = (const float*)d_in[9];
  const float* ln_s_b   = (const float*)d_in[10];
  const float* ln_t_g   = (const float*)d_in[11];
  const float* ln_t_b   = (const float*)d_in[12];
  const float* ln_m_g   = (const float*)d_in[13];
  const float* ln_m_b   = (const float*)d_in[14];
  const float* gate_up  = (const float*)d_in[15];
  const float* down_w   = (const float*)d_in[16];
  const int* expert_ids = (const int*)d_in[19];
  float* out = (float*)d_out;

  char* ws = (char*)d_ws;
  bf16* qkvsT   = (bf16*)(ws + 0);
  bf16* projsT  = (bf16*)(ws + 3538944);
  bf16* qkvtT   = (bf16*)(ws + 4718592);
  bf16* projtT  = (bf16*)(ws + 8257536);
  bf16* guT     = (bf16*)(ws + 9437184);
  bf16* downT   = (bf16*)(ws + 18874368);
  bf16* lnbuf   = (bf16*)(ws + 23592960);
  bf16* qkvbuf  = (bf16*)(ws + 42860544);   // qkv / permuted-inter buffer
  bf16* attnbuf = (bf16*)(ws + 100663296);
  bf16* x1b     = (bf16*)(ws + 119930880);  // bf16 residual spine (stage 1)
  bf16* x2b     = (bf16*)(ws + 139198464);  // bf16 residual spine (stage 2)
  int*  perm    = (int*)(ws + 158466048);
  int4* descs   = (int4*)(ws + 158472320);
  int*  meta    = (int*)(ws + 158473952);
  int*  invp    = (int*)(ws + 100663296);   // reuse attnbuf region (stage 3)

  const dim3 blk(256);

  transpose_qkv<<<dim3(12, 36, 2), blk, 0, stream>>>(qkv_w_s, qkv_w_t, qkvsT, qkvtT);
  transpose_768<<<dim3(12, 12, 6), blk, 0, stream>>>(proj_w_s, proj_w_t, down_w,
                                                     projsT, projtT, downT);
  transpose_gu<<<dim3(12, 24, 4), blk, 0, stream>>>(gate_up, guT);

  // stage 1: spatial
  ln_kernel<float><<<3136, blk, 0, stream>>>(x, ln_s_g, ln_s_b, lnbuf);
  gemmK64T<<<dim3(98 * 36), blk, 0, stream>>>(
      lnbuf, qkvsT, qkv_b_s, qkvbuf, 2304, 768, 36);
  attn_spatial<<<dim3(64, 12), dim3(1024), 0, stream>>>(qkvbuf, attnbuf);
  gemmDP<8, false, true, true, false, true, false, false><<<dim3(98 * 3), blk, 0, stream>>>(
      attnbuf, projsT, proj_b_s, x, nullptr, x1b, 768, 768, 3,
      nullptr, nullptr, nullptr);

  // stage 2: temporal (bf16 spine x2b; f32 `out` written only by down)
  ln_kernel<bf16><<<3136, blk, 0, stream>>>(x1b, ln_t_g, ln_t_b, lnbuf);
  gemmK64T<<<dim3(98 * 36), blk, 0, stream>>>(
      lnbuf, qkvtT, qkv_b_t, qkvbuf, 2304, 768, 36);
  attn_temporal<<<4704, blk, 0, stream>>>(qkvbuf, attnbuf);
  gemmDP<8, false, true, true, true, true, false, false><<<dim3(98 * 3), blk, 0, stream>>>(
      attnbuf, projtT, proj_b_t, x1b, nullptr, x2b, 768, 768, 3,
      nullptr, nullptr, nullptr);

  // stage 3: MoE MLP (expert-permuted activations; silu fused into gate_up)
  sort_moe<<<1, blk, 0, stream>>>(expert_ids, perm, invp, descs, meta);
  ln_moe_kernel<<<3136, blk, 0, stream>>>(x2b, ln_m_g, ln_m_b, invp, lnbuf);
  gemmK64<true, true><<<dim3(12 * 102), blk, 0, stream>>>(
      lnbuf, guT, nullptr, qkvbuf, 1536, 768, 12, descs, meta);
  gemmDP<8, true, false, true, true, false, false, true><<<dim3(3 * 102), blk, 0, stream>>>(
      qkvbuf, downT, nullptr, x2b, out, nullptr, 768, 768, 3,
      perm, descs, meta);
}

// Round 20
// 351.020 us; speedup vs baseline: 1.0355x; 1.0355x over previous
//
#include <hip/hip_runtime.h>

typedef __bf16 bf16;
typedef bf16 bf16x8 __attribute__((ext_vector_type(8)));
typedef float f32x4 __attribute__((ext_vector_type(4)));

#define BB 8
#define TT 8
#define SS 196
#define NTOK 1568           // T*S
#define ROWS 12544          // B*NTOK
#define HH 768
#define HD 64

__device__ __forceinline__ void gload16(const void* g, void* l) {
  __builtin_amdgcn_global_load_lds(
      (const __attribute__((address_space(1))) void*)g,
      (__attribute__((address_space(3))) void*)l, 16, 0, 0);
}

// ---------------- weight transposes f32[K][N] -> bf16[N][K] -----------------
__global__ __launch_bounds__(256)
void transpose_qkv(const float* __restrict__ in0, const float* __restrict__ in1,
                   bf16* __restrict__ out0, bf16* __restrict__ out1) {
  const int K = 768, N = 2304;
  const float* in = blockIdx.z ? in1 : in0;
  bf16* out = blockIdx.z ? out1 : out0;
  __shared__ float tile[64][65];
  const int k0 = blockIdx.x * 64, n0 = blockIdx.y * 64;
  const int tx = threadIdx.x & 63, ty = threadIdx.x >> 6;
  #pragma unroll
  for (int rr = ty; rr < 64; rr += 4)
    tile[rr][tx] = in[(size_t)(k0 + rr) * N + n0 + tx];
  __syncthreads();
  #pragma unroll
  for (int rr = ty; rr < 64; rr += 4)
    out[(size_t)(n0 + rr) * K + k0 + tx] = (bf16)tile[tx][rr];
}

// 768x768 set: z 0->proj_s, 1->proj_t, 2..5 -> down expert (z-2).
__global__ __launch_bounds__(256)
void transpose_768(const float* __restrict__ ps, const float* __restrict__ pt,
                   const float* __restrict__ dw,
                   bf16* __restrict__ ops, bf16* __restrict__ opt,
                   bf16* __restrict__ odw) {
  const int K = 768, N = 768;
  const int z = blockIdx.z;
  const float* in;
  bf16* out;
  if (z == 0)      { in = ps; out = ops; }
  else if (z == 1) { in = pt; out = opt; }
  else             { in = dw + (size_t)(z - 2) * K * N; out = odw + (size_t)(z - 2) * K * N; }
  __shared__ float tile[64][65];
  const int k0 = blockIdx.x * 64, n0 = blockIdx.y * 64;
  const int tx = threadIdx.x & 63, ty = threadIdx.x >> 6;
  #pragma unroll
  for (int rr = ty; rr < 64; rr += 4)
    tile[rr][tx] = in[(size_t)(k0 + rr) * N + n0 + tx];
  __syncthreads();
  #pragma unroll
  for (int rr = ty; rr < 64; rr += 4)
    out[(size_t)(n0 + rr) * K + k0 + tx] = (bf16)tile[tx][rr];
}

// gate_up transpose with column permutation: each 64-row stripe of guT =
// 32 gate rows + their 32 matching up rows (enables in-lane silu fusion).
__global__ __launch_bounds__(256)
void transpose_gu(const float* __restrict__ in, bf16* __restrict__ out) {
  const int K = 768, N = 1536;
  in  += (size_t)blockIdx.z * K * N;
  out += (size_t)blockIdx.z * K * N;
  __shared__ float tile[64][65];
  const int k0 = blockIdx.x * 64, n0 = blockIdx.y * 64;
  const int tx = threadIdx.x & 63, ty = threadIdx.x >> 6;
  const int s = n0 >> 6;
  #pragma unroll
  for (int rr = ty; rr < 64; rr += 4) {
    const int src = (tx < 32) ? (s * 32 + tx) : (768 + s * 32 + tx - 32);
    tile[rr][tx] = in[(size_t)(k0 + rr) * N + src];
  }
  __syncthreads();
  #pragma unroll
  for (int rr = ty; rr < 64; rr += 4)
    out[(size_t)(n0 + rr) * K + k0 + tx] = (bf16)tile[tx][rr];
}

// ---------------- layernorm: TI in -> bf16 out, wave per row ----------------
template<typename TI>
__global__ __launch_bounds__(256)
void ln_kernel(const TI* __restrict__ x, const float* __restrict__ g,
               const float* __restrict__ b, bf16* __restrict__ out) {
  const int row = blockIdx.x * 4 + (threadIdx.x >> 6);
  const int lane = threadIdx.x & 63;
  const TI* xr = x + (size_t)row * HH;
  float v[12];
  float sum = 0.f, sq = 0.f;
  #pragma unroll
  for (int i = 0; i < 12; ++i) {
    v[i] = (float)xr[lane + i * 64];
    sum += v[i];
    sq += v[i] * v[i];
  }
  #pragma unroll
  for (int off = 32; off > 0; off >>= 1) {
    sum += __shfl_xor(sum, off);
    sq  += __shfl_xor(sq, off);
  }
  const float mean = sum * (1.f / 768.f);
  const float var = sq * (1.f / 768.f) - mean * mean;
  const float inv = rsqrtf(var + 1e-6f);
  bf16* op = out + (size_t)row * HH;
  #pragma unroll
  for (int i = 0; i < 12; ++i) {
    const int c = lane + i * 64;
    op[c] = (bf16)((v[i] - mean) * inv * g[c] + b[c]);
  }
}

// layernorm (bf16 in) + expert permutation: row (b,n) -> inv[n]*8 + b.
__global__ __launch_bounds__(256)
void ln_moe_kernel(const bf16* __restrict__ x, const float* __restrict__ g,
                   const float* __restrict__ b, const int* __restrict__ invp,
                   bf16* __restrict__ out) {
  const int row = blockIdx.x * 4 + (threadIdx.x >> 6);
  const int lane = threadIdx.x & 63;
  const bf16* xr = x + (size_t)row * HH;
  float v[12];
  float sum = 0.f, sq = 0.f;
  #pragma unroll
  for (int i = 0; i < 12; ++i) {
    v[i] = (float)xr[lane + i * 64];
    sum += v[i];
    sq += v[i] * v[i];
  }
  #pragma unroll
  for (int off = 32; off > 0; off >>= 1) {
    sum += __shfl_xor(sum, off);
    sq  += __shfl_xor(sq, off);
  }
  const float mean = sum * (1.f / 768.f);
  const float var = sq * (1.f / 768.f) - mean * mean;
  const float inv = rsqrtf(var + 1e-6f);
  const int bb = row / NTOK, n = row - bb * NTOK;
  bf16* op = out + ((size_t)invp[n] * 8 + bb) * HH;
  #pragma unroll
  for (int i = 0; i < 12; ++i) {
    const int c = lane + i * 64;
    op[c] = (bf16)((v[i] - mean) * inv * g[c] + b[c]);
  }
}

// ---------------- K64 GEMM: 128x128, BK=64, 2 bufs, 12 phases, 2 blk/CU -----
// The measured-best qkv/gate_up structure (R17/R18): per phase vmcnt ->
// barrier -> {16 ds_read_b128 || stage tile t+1 (t>=1)} -> setprio(1)
// 32 MFMA setprio(0). buf[t&1]; stage(t+1)@phase t targets the buffer whose
// reads finished in phase t-1 (phase-t barrier proves all waves passed).
// vmcnt(8)@p0, vmcnt(0) after (stage issued a full phase earlier). Swizzle:
// store seg (c&7)^(row&7), read chunk ((kg*4+lg)^(lr&7)) (rule #21).
// MOE (gate_up): permuted-dense A (row=pos*8+b), desc d -> M0=d.y*8,
// contiguous staging; GUFUSE silu(g)*u epilogue, stripe=(N0>>6)+wc.
template<bool MOE, bool GUFUSE>
__global__ __launch_bounds__(256, 2)
void gemmK64(const bf16* __restrict__ A, const bf16* __restrict__ BT,
             const float* __restrict__ bias, bf16* __restrict__ outB,
             int N, int K, int NMT,
             const int4* __restrict__ descs, const int* __restrict__ meta) {
  __shared__ __align__(16) bf16 lds[2 * 16384];   // 64 KB
  const int tid = threadIdx.x;
  const int G = gridDim.x;
  int work;
  {
    const int q = G >> 3, r = G & 7, xcd = blockIdx.x & 7, pos = blockIdx.x >> 3;
    work = (xcd < r ? xcd * (q + 1) : r * (q + 1) + (xcd - r) * q) + pos;
  }
  int M0, N0, ncnt = 16;
  if constexpr (MOE) {
    const int ntile = work % NMT, desc = work / NMT;
    if (desc >= meta[0]) return;
    int4 d = descs[desc];
    BT += (size_t)d.x * N * K;
    ncnt = d.z;
    N0 = ntile * 128;
    M0 = d.y * 8;                                 // permuted-dense A row base
  } else {
    const int mt = work / NMT, nt = work % NMT;   // n-fastest
    M0 = mt * 128;
    N0 = nt * 128;
  }

  const int w = tid >> 6, lane = tid & 63;
  const int wr = w >> 1, wc = w & 1;
  const int lr = lane & 15, lg = lane >> 4;

  // staging: 1024 chunks/operand; chunk c -> row c>>3, store seg c&7,
  // source seg (c&7)^(row&7).
  size_t aG[4], bG[4]; int L[4];
  #pragma unroll
  for (int i = 0; i < 4; ++i) {
    const int c = tid + i * 256;
    const int row = c >> 3, seg = (c & 7) ^ (row & 7);
    int ar = M0 + row;
    if constexpr (MOE) ar = ar < ROWS ? ar : ROWS - 1;
    aG[i] = (size_t)ar * K + seg * 8;
    bG[i] = (size_t)(N0 + row) * K + seg * 8;
    L[i] = c * 8;
  }
  auto STG = [&](int kt) {
    bf16* buf = lds + (kt & 1) * 16384;
    const int ko = kt << 6;
    #pragma unroll
    for (int i = 0; i < 4; ++i) gload16(A + aG[i] + ko, buf + L[i]);
    #pragma unroll
    for (int i = 0; i < 4; ++i) gload16(BT + bG[i] + ko, buf + 8192 + L[i]);
  };

  f32x4 acc[4][4] = {};
  const int NT = K >> 6;                          // 12 at K=768

  STG(0); STG(1);

  for (int t = 0; t < NT; ++t) {
    if (t == 0) { asm volatile("s_waitcnt vmcnt(8)" ::: "memory"); }
    else        { asm volatile("s_waitcnt vmcnt(0)" ::: "memory"); }
    __builtin_amdgcn_s_barrier();
    asm volatile("" ::: "memory");

    const bf16* Ab = lds + (t & 1) * 16384;
    const bf16* Bb = Ab + 8192;
    bf16x8 a[8], b[8];
    #pragma unroll
    for (int mf = 0; mf < 4; ++mf) {
      const int row = wr * 64 + mf * 16 + lr;
      #pragma unroll
      for (int kg = 0; kg < 2; ++kg)
        a[mf * 2 + kg] = *(const bf16x8*)(Ab + row * 64 + ((kg * 4 + lg) ^ (lr & 7)) * 8);
    }
    #pragma unroll
    for (int nf = 0; nf < 4; ++nf) {
      const int row = wc * 64 + nf * 16 + lr;
      #pragma unroll
      for (int kg = 0; kg < 2; ++kg)
        b[nf * 2 + kg] = *(const bf16x8*)(Bb + row * 64 + ((kg * 4 + lg) ^ (lr & 7)) * 8);
    }
    if (t >= 1 && t + 1 < NT) STG(t + 1);

    __builtin_amdgcn_s_setprio(1);
    #pragma unroll
    for (int mf = 0; mf < 4; ++mf)
      #pragma unroll
      for (int nf = 0; nf < 4; ++nf) {
        f32x4 c = acc[mf][nf];
        c = __builtin_amdgcn_mfma_f32_16x16x32_bf16(a[mf * 2 + 0], b[nf * 2 + 0], c, 0, 0, 0);
        c = __builtin_amdgcn_mfma_f32_16x16x32_bf16(a[mf * 2 + 1], b[nf * 2 + 1], c, 0, 0, 0);
        acc[mf][nf] = c;
      }
    __builtin_amdgcn_s_setprio(0);
    asm volatile("" ::: "memory");
  }

  #pragma unroll
  for (int m = 0; m < 4; ++m) {
    #pragma unroll
    for (int j = 0; j < 4; ++j) {
      const int r = wr * 64 + m * 16 + lg * 4 + j;
      if (MOE && ((r >> 3) >= ncnt)) continue;
      if constexpr (GUFUSE) {
        // wave covers one 64-col gu stripe (32 gate | 32 up)
        const size_t rbase = (size_t)(M0 + r) * 768;
        const int stripe = (N0 >> 6) + wc;
        #pragma unroll
        for (int n = 0; n < 2; ++n) {
          const int icol = stripe * 32 + n * 16 + lr;
          const float g = acc[m][n][j], u = acc[m][n + 2][j];
          outB[rbase + icol] = (bf16)(g / (1.f + __expf(-g)) * u);
        }
      } else {
        const size_t rbase = (size_t)(M0 + r) * N;
        #pragma unroll
        for (int n = 0; n < 4; ++n) {
          const int gcol = N0 + wc * 64 + n * 16 + lr;
          outB[rbase + gcol] = (bf16)(acc[m][n][j] + bias[gcol]);
        }
      }
    }
  }
}

// ---------------- deep-pipe GEMM: 128x(NF*32), BK=32, 3 LDS bufs, 2 blk/CU --
// (proj/down NF=8 single round; schedule unchanged from R16.)
template<int NF, bool MOE, bool BIAS, bool RESID, bool RB16, bool OBF16,
         bool GUFUSE, bool SCATTER>
__global__ __launch_bounds__(256, 2)
void gemmDP(const bf16* __restrict__ A, const bf16* __restrict__ BT,
            const float* __restrict__ bias, const void* __restrict__ resid,
            float* __restrict__ outF, bf16* __restrict__ outB,
            int N, int K, int NMT,
            const int* __restrict__ perm, const int4* __restrict__ descs,
            const int* __restrict__ meta) {
  constexpr int BUFE = 4096 + NF * 1024;          // elems per buffer
  __shared__ __align__(16) bf16 lds[3 * BUFE];
  __shared__ int rowLds[128];

  const int tid = threadIdx.x;
  const int G = gridDim.x;
  int work;
  {
    const int q = G >> 3, r = G & 7, xcd = blockIdx.x & 7, pos = blockIdx.x >> 3;
    work = (xcd < r ? xcd * (q + 1) : r * (q + 1) + (xcd - r) * q) + pos;
  }
  int M0 = 0, N0, ncnt = 16;
  if constexpr (MOE) {
    const int ntile = work % NMT, desc = work / NMT;
    if (desc >= meta[0]) return;
    int4 d = descs[desc];
    BT += (size_t)d.x * N * K;
    ncnt = d.z;
    N0 = ntile * (NF * 32);
    M0 = d.y * 8;                       // permuted-dense A row base
    if constexpr (SCATTER) {
      if (tid < 128) {
        const int nl = tid >> 3, b = tid & 7;
        const int n = perm[d.y + (nl < ncnt ? nl : ncnt - 1)];
        rowLds[tid] = b * NTOK + n;
      }
      __syncthreads();
    }
  } else {
    const int mt = work / NMT, nt = work % NMT;   // n-fastest (proven)
    M0 = mt * 128;
    N0 = nt * (NF * 32);
  }

  const int w = tid >> 6, lane = tid & 63;
  const int wr = w >> 1, wc = w & 1;
  const int lr = lane & 15, lg = lane >> 4;

  const int r0 = tid >> 2;                          // 0..63
  const int sseg = ((tid & 3) ^ ((tid >> 3) & 3)) * 8;
  int arow0 = M0 + r0, arow1 = M0 + 64 + r0;
  if constexpr (MOE) {
    arow0 = arow0 < ROWS ? arow0 : ROWS - 1;
    arow1 = arow1 < ROWS ? arow1 : ROWS - 1;
  }
  const bf16* aP0 = A + (size_t)arow0 * K + sseg;
  const bf16* aP1 = A + (size_t)arow1 * K + sseg;
  const bf16* bP[NF / 2];
  #pragma unroll
  for (int i = 0; i < NF / 2; ++i)
    bP[i] = BT + (size_t)(N0 + i * 64 + r0) * K + sseg;

  auto STG = [&](int kt) {
    bf16* buf = lds + (kt % 3) * BUFE;
    const int ko = kt << 5;
    gload16(aP0 + ko, buf + tid * 8);
    gload16(aP1 + ko, buf + 2048 + tid * 8);
    #pragma unroll
    for (int i = 0; i < NF / 2; ++i)
      gload16(bP[i] + ko, buf + 4096 + i * 2048 + tid * 8);
  };

  const int axr = (lg ^ ((lr >> 1) & 3)) * 8;       // read-side chunk XOR

  f32x4 acc[4][NF] = {};
  const int NT = K >> 5;                            // 24 at K=768

  STG(0); STG(1);

  for (int t = 0; t < NT; ++t) {
    if (t + 1 < NT) {
      if constexpr (NF == 8) { asm volatile("s_waitcnt vmcnt(6)" ::: "memory"); }
      else                   { asm volatile("s_waitcnt vmcnt(4)" ::: "memory"); }
    } else {
      asm volatile("s_waitcnt vmcnt(0)" ::: "memory");
    }
    __builtin_amdgcn_s_barrier();
    asm volatile("" ::: "memory");

    const bf16* Ab = lds + (t % 3) * BUFE;
    const bf16* Bb = Ab + 4096;
    bf16x8 a[4], b[NF];
    #pragma unroll
    for (int mf = 0; mf < 4; ++mf) {
      const int row = wr * 64 + mf * 16 + lr;
      a[mf] = *(const bf16x8*)(Ab + row * 32 + axr);
    }
    #pragma unroll
    for (int nf = 0; nf < NF; ++nf) {
      const int row = wc * (NF * 16) + nf * 16 + lr;
      b[nf] = *(const bf16x8*)(Bb + row * 32 + axr);
    }
    if (t + 2 < NT) STG(t + 2);

    __builtin_amdgcn_s_setprio(1);
    #pragma unroll
    for (int mf = 0; mf < 4; ++mf)
      #pragma unroll
      for (int nf = 0; nf < NF; ++nf)
        acc[mf][nf] = __builtin_amdgcn_mfma_f32_16x16x32_bf16(a[mf], b[nf], acc[mf][nf], 0, 0, 0);
    __builtin_amdgcn_s_setprio(0);
    asm volatile("" ::: "memory");
  }

  #pragma unroll
  for (int m = 0; m < 4; ++m) {
    #pragma unroll
    for (int j = 0; j < 4; ++j) {
      const int r = wr * 64 + m * 16 + lg * 4 + j;
      if (MOE && ((r >> 3) >= ncnt)) continue;
      size_t grow;
      if constexpr (MOE && SCATTER) grow = (size_t)rowLds[r];
      else                          grow = (size_t)(M0 + r);
      if constexpr (GUFUSE) {
        const size_t rbase = grow * 768;
        #pragma unroll
        for (int n = 0; n < NF; ++n) {
          if ((n & 3) >= 2) continue;
          const int stripe = (N0 >> 6) + wc * (NF / 4) + (n >> 2);
          const int icol = stripe * 32 + (n & 3) * 16 + lr;
          const float g = acc[m][n][j], u = acc[m][n + 2][j];
          outB[rbase + icol] = (bf16)(g / (1.f + __expf(-g)) * u);
        }
      } else {
        const size_t rbase = grow * N;
        #pragma unroll
        for (int n = 0; n < NF; ++n) {
          const int gcol = N0 + wc * (NF * 16) + n * 16 + lr;
          float v = acc[m][n][j];
          if constexpr (BIAS)  v += bias[gcol];
          if constexpr (RESID) {
            if constexpr (RB16) v += (float)((const bf16*)resid)[rbase + gcol];
            else                v += ((const float*)resid)[rbase + gcol];
          }
          if constexpr (OBF16) outB[rbase + gcol] = (bf16)v;
          else                 outF[rbase + gcol] = v;
        }
      }
    }
  }
}

// ---------------- spatial attention (MFMA): block per (bp, h), 16 waves -----
#define SPAD 208
#define VST 232
__global__ __launch_bounds__(1024, 1)
void attn_spatial(const bf16* __restrict__ qkv, bf16* __restrict__ out) {
  __shared__ __align__(16) bf16 Ks[SPAD * 64];
  __shared__ __align__(16) bf16 Vt[64 * VST];
  __shared__ __align__(16) bf16 Pb[13][16 * VST];

  const int bp = blockIdx.x, h = blockIdx.y;
  const int tid = threadIdx.x;
  const int w = tid >> 6, lane = tid & 63;
  const int lr = lane & 15, lg = lane >> 4;
  const size_t base = (size_t)bp * SS * 2304 + h * HD;

  for (int cb = w * 64; cb < SPAD * 8; cb += 1024) {
    const int c = cb + lane;
    const int row = c >> 3, seg = c & 7;
    const int srow = row < SS ? row : SS - 1;
    const int sseg = seg ^ (row & 7);
    gload16(qkv + base + (size_t)srow * 2304 + 768 + sseg * 8, Ks + cb * 8);
  }
  for (int t = tid; t < 224 * 8; t += 1024) {
    const int k = t >> 3, dseg = t & 7;
    const int sk = k < SS ? k : SS - 1;
    bf16x8 v = *(const bf16x8*)(qkv + base + (size_t)sk * 2304 + 1536 + dseg * 8);
    #pragma unroll
    for (int i = 0; i < 8; ++i) Vt[(dseg * 8 + i) * VST + k] = v[i];
  }
  if (w < 13) {
    bf16* Pw = Pb[w];
    for (int i = lane; i < 256; i += 64)
      Pw[(i >> 4) * VST + 208 + (i & 15)] = (bf16)0.f;
  }
  __syncthreads();

  for (int t = w; t < 13; t += 16) {
    bf16* Pw = Pb[t];
    const int q0 = t * 16;
    const int qr = q0 + lr;
    const bf16* qp = qkv + base + (size_t)(qr < SS ? qr : SS - 1) * 2304 + lg * 8;
    const bf16x8 af0 = *(const bf16x8*)qp;
    const bf16x8 af1 = *(const bf16x8*)(qp + 32);

    f32x4 sc[13];
    #pragma unroll
    for (int f = 0; f < 13; ++f) sc[f] = (f32x4){0.f, 0.f, 0.f, 0.f};
    #pragma unroll
    for (int f = 0; f < 13; ++f) {
      const int key = f * 16 + lr;
      const bf16x8 bv0 = *(const bf16x8*)&Ks[key * 64 + ((lg) ^ (key & 7)) * 8];
      const bf16x8 bv1 = *(const bf16x8*)&Ks[key * 64 + ((4 + lg) ^ (key & 7)) * 8];
      sc[f] = __builtin_amdgcn_mfma_f32_16x16x32_bf16(af0, bv0, sc[f], 0, 0, 0);
      sc[f] = __builtin_amdgcn_mfma_f32_16x16x32_bf16(af1, bv1, sc[f], 0, 0, 0);
    }
    #pragma unroll
    for (int f = 0; f < 13; ++f)
      #pragma unroll
      for (int j = 0; j < 4; ++j) sc[f][j] *= 0.125f;
    if (192 + lr >= SS)
      #pragma unroll
      for (int j = 0; j < 4; ++j) sc[12][j] = -1e30f;

    float mx[4], ls[4];
    #pragma unroll
    for (int j = 0; j < 4; ++j) {
      float m = sc[0][j];
      #pragma unroll
      for (int f = 1; f < 13; ++f) m = fmaxf(m, sc[f][j]);
      #pragma unroll
      for (int off = 1; off < 16; off <<= 1) m = fmaxf(m, __shfl_xor(m, off));
      mx[j] = m;
    }
    #pragma unroll
    for (int j = 0; j < 4; ++j) ls[j] = 0.f;
    #pragma unroll
    for (int f = 0; f < 13; ++f) {
      #pragma unroll
      for (int j = 0; j < 4; ++j) {
        const float p = __expf(sc[f][j] - mx[j]);
        ls[j] += p;
        Pw[(lg * 4 + j) * VST + f * 16 + lr] = (bf16)p;
      }
    }
    #pragma unroll
    for (int j = 0; j < 4; ++j) {
      #pragma unroll
      for (int off = 1; off < 16; off <<= 1) ls[j] += __shfl_xor(ls[j], off);
      ls[j] = 1.f / ls[j];
    }

    f32x4 oacc[4];
    #pragma unroll
    for (int n = 0; n < 4; ++n) oacc[n] = (f32x4){0.f, 0.f, 0.f, 0.f};
    #pragma unroll
    for (int kb = 0; kb < 7; ++kb) {
      const bf16x8 pa = *(const bf16x8*)&Pw[lr * VST + kb * 32 + lg * 8];
      #pragma unroll
      for (int n = 0; n < 4; ++n) {
        const bf16x8 bv = *(const bf16x8*)&Vt[(n * 16 + lr) * VST + kb * 32 + lg * 8];
        oacc[n] = __builtin_amdgcn_mfma_f32_16x16x32_bf16(pa, bv, oacc[n], 0, 0, 0);
      }
    }
    #pragma unroll
    for (int j = 0; j < 4; ++j) {
      const int row = q0 + lg * 4 + j;
      if (row < SS) {
        bf16* op = out + ((size_t)bp * SS + row) * 768 + h * HD;
        #pragma unroll
        for (int n = 0; n < 4; ++n) op[n * 16 + lr] = (bf16)(oacc[n][j] * ls[j]);
      }
    }
  }
}

// ---------------- temporal attention: wave per (b, s, h), T=8 ---------------
__global__ __launch_bounds__(256)
void attn_temporal(const bf16* __restrict__ qkv, bf16* __restrict__ out) {
  const int pair = blockIdx.x * 4 + (threadIdx.x >> 6);
  const int lane = threadIdx.x & 63;
  const int h = pair % 12;
  const int bs = pair / 12;
  const int b = bs / SS, s = bs - b * SS;
  const size_t row0 = (size_t)b * NTOK + s;
  const int q = lane >> 3, k = lane & 7;
  const bf16* qr = qkv + (row0 + (size_t)q * SS) * 2304 + h * HD;
  const bf16* kr = qkv + (row0 + (size_t)k * SS) * 2304 + 768 + h * HD;
  float sc = 0.f;
  #pragma unroll
  for (int j = 0; j < 8; ++j) {
    bf16x8 qv = ((const bf16x8*)qr)[j];
    bf16x8 kv = ((const bf16x8*)kr)[j];
    #pragma unroll
    for (int d = 0; d < 8; ++d) sc += (float)qv[d] * (float)kv[d];
  }
  sc *= 0.125f;
  float mxv = sc;
  #pragma unroll
  for (int off = 1; off < 8; off <<= 1) mxv = fmaxf(mxv, __shfl_xor(mxv, off));
  float p = __expf(sc - mxv);
  float sum = p;
  #pragma unroll
  for (int off = 1; off < 8; off <<= 1) sum += __shfl_xor(sum, off);
  p /= sum;

  const int dg = lane & 7;
  float o[8] = {0, 0, 0, 0, 0, 0, 0, 0};
  #pragma unroll
  for (int kk = 0; kk < 8; ++kk) {
    const float pk = __shfl(p, (lane & 56) + kk);
    const bf16* vr = qkv + (row0 + (size_t)kk * SS) * 2304 + 1536 + h * HD + dg * 8;
    bf16x8 vv = *(const bf16x8*)vr;
    #pragma unroll
    for (int j = 0; j < 8; ++j) o[j] += pk * (float)vv[j];
  }
  bf16* op = out + (row0 + (size_t)q * SS) * 768 + h * HD + dg * 8;
  bf16x8 ov;
  #pragma unroll
  for (int j = 0; j < 8; ++j) ov[j] = (bf16)o[j];
  *(bf16x8*)op = ov;
}

// ---------------- MoE: bucket tokens by expert; perm, inv, 16-pos descs -----
__global__ __launch_bounds__(256)
void sort_moe(const int* __restrict__ eids, int* __restrict__ perm,
              int* __restrict__ invp, int4* __restrict__ descs,
              int* __restrict__ meta) {
  __shared__ int cnt[4], base[4], cur[4];
  const int tid = threadIdx.x;
  if (tid < 4) cnt[tid] = 0;
  __syncthreads();
  for (int n = tid; n < NTOK; n += 256) atomicAdd(&cnt[eids[n]], 1);
  __syncthreads();
  if (tid == 0) {
    int off = 0;
    for (int e = 0; e < 4; ++e) { base[e] = off; cur[e] = off; off += cnt[e]; }
  }
  __syncthreads();
  for (int n = tid; n < NTOK; n += 256) {
    const int pos = atomicAdd(&cur[eids[n]], 1);
    perm[pos] = n;
    invp[n] = pos;
  }
  if (tid == 0) {
    int t = 0;
    for (int e = 0; e < 4; ++e)
      for (int st = 0; st < cnt[e]; st += 16) {
        const int c = cnt[e] - st;
        descs[t++] = make_int4(e, base[e] + st, c < 16 ? c : 16, 0);
      }
    meta[0] = t;
  }
}

// ---------------- launch ------------------------------------------------------
extern "C" void kernel_launch(void* const* d_in, const int* in_sizes, int n_in,
                              void* d_out, int out_size, void* d_ws, size_t ws_size,
                              hipStream_t stream) {
  (void)in_sizes; (void)n_in; (void)out_size; (void)ws_size;
  const float* x        = (const float*)d_in[0];
  const float* qkv_w_s  = (const float*)d_in[1];
  const float* qkv_b_s  = (const float*)d_in[2];
  const float* proj_w_s = (const float*)d_in[3];
  const float* proj_b_s = (const float*)d_in[4];
  const float* qkv_w_t  = (const float*)d_in[5];
  const float* qkv_b_t  = (const float*)d_in[6];
  const float* proj_w_t = (const float*)d_in[7];
  const float* proj_b_t = (const float*)d_in[8];
  const float* ln_s_g   = (const float*)d_in[9];
  const float* ln_s_b   = (const float*)d_in[10];
  const float* ln_t_g   = (const float*)d_in[11];
  const float* ln_t_b   = (const float*)d_in[12];
  const float* ln_m_g   = (const float*)d_in[13];
  const float* ln_m_b   = (const float*)d_in[14];
  const float* gate_up  = (const float*)d_in[15];
  const float* down_w   = (const float*)d_in[16];
  const int* expert_ids = (const int*)d_in[19];
  float* out = (float*)d_out;

  char* ws = (char*)d_ws;
  bf16* qkvsT   = (bf16*)(ws + 0);
  bf16* projsT  = (bf16*)(ws + 3538944);
  bf16* qkvtT   = (bf16*)(ws + 4718592);
  bf16* projtT  = (bf16*)(ws + 8257536);
  bf16* guT     = (bf16*)(ws + 9437184);
  bf16* downT   = (bf16*)(ws + 18874368);
  bf16* lnbuf   = (bf16*)(ws + 23592960);
  bf16* qkvbuf  = (bf16*)(ws + 42860544);   // qkv / permuted-inter buffer
  bf16* attnbuf = (bf16*)(ws + 100663296);
  bf16* x1b     = (bf16*)(ws + 119930880);  // bf16 residual spine (stage 1)
  bf16* x2b     = (bf16*)(ws + 139198464);  // bf16 residual spine (stage 2)
  int*  perm    = (int*)(ws + 158466048);
  int4* descs   = (int4*)(ws + 158472320);
  int*  meta    = (int*)(ws + 158473952);
  int*  invp    = (int*)(ws + 100663296);   // reuse attnbuf region (stage 3)

  const dim3 blk(256);

  transpose_qkv<<<dim3(12, 36, 2), blk, 0, stream>>>(qkv_w_s, qkv_w_t, qkvsT, qkvtT);
  transpose_768<<<dim3(12, 12, 6), blk, 0, stream>>>(proj_w_s, proj_w_t, down_w,
                                                     projsT, projtT, downT);
  transpose_gu<<<dim3(12, 24, 4), blk, 0, stream>>>(gate_up, guT);

  // stage 1: spatial
  ln_kernel<float><<<3136, blk, 0, stream>>>(x, ln_s_g, ln_s_b, lnbuf);
  gemmK64<false, false><<<dim3(98 * 18), blk, 0, stream>>>(
      lnbuf, qkvsT, qkv_b_s, qkvbuf, 2304, 768, 18, nullptr, nullptr);
  attn_spatial<<<dim3(64, 12), dim3(1024), 0, stream>>>(qkvbuf, attnbuf);
  gemmDP<8, false, true, true, false, true, false, false><<<dim3(98 * 3), blk, 0, stream>>>(
      attnbuf, projsT, proj_b_s, x, nullptr, x1b, 768, 768, 3,
      nullptr, nullptr, nullptr);

  // stage 2: temporal (bf16 spine x2b; f32 `out` written only by down)
  ln_kernel<bf16><<<3136, blk, 0, stream>>>(x1b, ln_t_g, ln_t_b, lnbuf);
  gemmK64<false, false><<<dim3(98 * 18), blk, 0, stream>>>(
      lnbuf, qkvtT, qkv_b_t, qkvbuf, 2304, 768, 18, nullptr, nullptr);
  attn_temporal<<<4704, blk, 0, stream>>>(qkvbuf, attnbuf);
  gemmDP<8, false, true, true, true, true, false, false><<<dim3(98 * 3), blk, 0, stream>>>(
      attnbuf, projtT, proj_b_t, x1b, nullptr, x2b, 768, 768, 3,
      nullptr, nullptr, nullptr);

  // stage 3: MoE MLP (expert-permuted activations; silu fused into gate_up)
  sort_moe<<<1, blk, 0, stream>>>(expert_ids, perm, invp, descs, meta);
  ln_moe_kernel<<<3136, blk, 0, stream>>>(x2b, ln_m_g, ln_m_b, invp, lnbuf);
  gemmK64<true, true><<<dim3(12 * 102), blk, 0, stream>>>(
      lnbuf, guT, nullptr, qkvbuf, 1536, 768, 12, descs, meta);
  gemmDP<8, true, false, true, true, false, false, true><<<dim3(3 * 102), blk, 0, stream>>>(
      qkvbuf, downT, nullptr, x2b, out, nullptr, 768, 768, 3,
      perm, descs, meta);
}